// Round 18
// baseline (304.519 us; speedup 1.0000x reference)
//
#include <hip/hip_runtime.h>

#define N_NODES 50000
#define N_EDGES 800000
#define DIM     200
#define NBLK    100   // B blocks of S=2
#define NRELS   230
#define NB_SCAN 196   // ceil(N_NODES/256)
#define KPAD    224   // feature-row stride (bf16 buffers)
#define KPN     256   // gemm output-column pad (8 nt of 32)
#define NROWPAD 50048
#define NFRAG8  (8 * 14 * 64)   // fragment-packed weights: 8 nt x 14 ks x 64 lanes (x8 bf16)
#define EPADMAX (N_EDGES + 3 * N_NODES + 16)   // padded CSR capacity
#define DUMMYROW 50000                          // zero bf16 row for pad edges

typedef __attribute__((ext_vector_type(8)))  short short8;
typedef __attribute__((ext_vector_type(16))) float f32x16;

__device__ __forceinline__ unsigned short f2bf(float f) {
    unsigned u = __float_as_uint(f);
    u += 0x7fffu + ((u >> 16) & 1u);        // RNE (inputs finite)
    return (unsigned short)(u >> 16);
}

__device__ __forceinline__ float bflo(unsigned u) { return __uint_as_float(u << 16); }
__device__ __forceinline__ float bfhi(unsigned u) { return __uint_as_float(u & 0xffff0000u); }
__device__ __forceinline__ float b2f(unsigned short u) { return __uint_as_float((unsigned)u << 16); }

__device__ __forceinline__ float tanh_fast(float x) {
    float xa = fminf(fmaxf(x, -15.0f), 15.0f);
    float e = __expf(2.0f * xa);
    return (e - 1.0f) / (e + 1.0f);
}

__device__ __forceinline__ int uread(int v, int l) {
    return __builtin_amdgcn_readlane(v, l);
}

// ---- bf16 dot2: 1 instruction for a0*b0+a1*b1+c when available
#if __has_builtin(__builtin_amdgcn_fdot2_f32_bf16)
typedef __bf16 bf16x2 __attribute__((ext_vector_type(2)));
__device__ __forceinline__ float dot2bf(unsigned a, unsigned b, float c) {
    return __builtin_amdgcn_fdot2_f32_bf16(
        __builtin_bit_cast(bf16x2, a), __builtin_bit_cast(bf16x2, b), c, false);
}
#define CMP4(XU, WU)                                                    \
    { m0 = dot2bf(XU.x, WU.x, m0); m1 = dot2bf(XU.x, WU.y, m1);         \
      m2 = dot2bf(XU.y, WU.z, m2); m3 = dot2bf(XU.y, WU.w, m3); }
#else
#define CMP4(XU, WU)                                                    \
    { float x0 = bflo(XU.x), x1 = bfhi(XU.x);                           \
      float x2 = bflo(XU.y), x3 = bfhi(XU.y);                           \
      m0 += x0 * bflo(WU.x) + x1 * bfhi(WU.x);                          \
      m1 += x0 * bflo(WU.y) + x1 * bfhi(WU.y);                          \
      m2 += x2 * bflo(WU.z) + x3 * bfhi(WU.z);                          \
      m3 += x2 * bflo(WU.w) + x3 * bfhi(WU.w); }
#endif

// LDS swizzles: 512B-stride rows (gemm1) and 256B-stride rows (gemm2 halves)
#define SWZ5(rr, off) ((unsigned)((rr) * 512 + (off)) ^ ((unsigned)((rr) & 15) << 4))
#define SWZH(rr, off) ((unsigned)((rr) * 256 + (off)) ^ ((unsigned)((rr) & 15) << 4))

// ---------------------------------------------------------------- degree + rank (ONE atomic pass)
__global__ void deg_rank(const int* __restrict__ dst, int* __restrict__ degi,
                         int* __restrict__ rank) {
    int idx = blockIdx.x * blockDim.x + threadIdx.x;
    if (idx >= N_EDGES / 8) return;
    int e0 = idx * 8;
    int4 da = *(const int4*)(dst + e0);
    int4 db = *(const int4*)(dst + e0 + 4);
    int r0 = atomicAdd(&degi[da.x], 1);
    int r1 = atomicAdd(&degi[da.y], 1);
    int r2 = atomicAdd(&degi[da.z], 1);
    int r3 = atomicAdd(&degi[da.w], 1);
    int r4 = atomicAdd(&degi[db.x], 1);
    int r5 = atomicAdd(&degi[db.y], 1);
    int r6 = atomicAdd(&degi[db.z], 1);
    int r7 = atomicAdd(&degi[db.w], 1);
    *(int4*)(rank + e0)     = make_int4(r0, r1, r2, r3);
    *(int4*)(rank + e0 + 4) = make_int4(r4, r5, r6, r7);
}

// ---------------------------------------------------------------- feature prep, vectorized
__global__ void prep_feat2(const float* __restrict__ x, const float* __restrict__ de,
                           unsigned short* __restrict__ xb, unsigned short* __restrict__ h0b) {
    const int HALF = NROWPAD * 28;
    int idx = blockIdx.x * blockDim.x + threadIdx.x;
    if (idx >= 2 * HALF) return;
    const float* src = (idx < HALF) ? x : de;
    unsigned short* o = (idx < HALF) ? xb : h0b;
    int j = (idx < HALF) ? idx : idx - HALF;
    int row = j / 28, c8 = j % 28;
    uint4 pk = {0, 0, 0, 0};
    if (row < N_NODES && c8 < 25) {
        const float* p = src + (size_t)row * DIM + c8 * 8;
        float4 a = *(const float4*)p;
        float4 b = *(const float4*)(p + 4);
        pk.x = (unsigned)f2bf(a.x) | ((unsigned)f2bf(a.y) << 16);
        pk.y = (unsigned)f2bf(a.z) | ((unsigned)f2bf(a.w) << 16);
        pk.z = (unsigned)f2bf(b.x) | ((unsigned)f2bf(b.y) << 16);
        pk.w = (unsigned)f2bf(b.z) | ((unsigned)f2bf(b.w) << 16);
    }
    *(uint4*)(o + (size_t)j * 8) = pk;
}

// ---------------------------------------------------------------- small weight preps:
#define PS_C (2 * NRELS * NBLK)
#define PS_D (3 * NFRAG8)
#define PS_E ((DIM + 1) * DIM)
#define PS_TOTAL (PS_C + PS_D + PS_E)

__global__ __launch_bounds__(256) void prep_small(
        const float* __restrict__ w1, const float* __restrict__ w2,
        unsigned short* __restrict__ w1b, unsigned short* __restrict__ w2b,
        const float* __restrict__ lw1, const float* __restrict__ wih,
        const float* __restrict__ whh,
        unsigned short* __restrict__ w1f, unsigned short* __restrict__ wihf,
        unsigned short* __restrict__ whhf,
        const float* __restrict__ lw2, const float* __restrict__ b2,
        const float* __restrict__ b_ih, const float* __restrict__ b_hh,
        float* __restrict__ Mt) {
    int idx = blockIdx.x * blockDim.x + threadIdx.x;
    if (idx < PS_C) {
        const int HALF = NRELS * NBLK;
        const float* w = (idx < HALF) ? w1 : w2;
        unsigned short* o = (idx < HALF) ? w1b : w2b;
        int j = (idx < HALF) ? idx : idx - HALF;
        float4 v = *(const float4*)(w + (size_t)j * 4);  // w00,w01,w10,w11
        unsigned c0 = (unsigned)f2bf(v.x) | ((unsigned)f2bf(v.z) << 16);
        unsigned c1 = (unsigned)f2bf(v.y) | ((unsigned)f2bf(v.w) << 16);
        *(uint2*)(o + (size_t)j * 4) = make_uint2(c0, c1);
        return;
    }
    idx -= PS_C;
    if (idx < PS_D) {
        int sec = idx / NFRAG8, f = idx % NFRAG8;
        const float* w = (sec == 0) ? lw1 : (sec == 1) ? wih : whh;
        unsigned short* o = (sec == 0) ? w1f : (sec == 1) ? wihf : whhf;
        int l = f & 63;
        int ks = (f >> 6) % 14;
        int nt = f / (14 * 64);
        int n  = nt * 32 + (l & 31);
        int k0 = ks * 16 + (l >> 5) * 8;
        unsigned short v[8];
        #pragma unroll
        for (int j = 0; j < 8; ++j) {
            int k = k0 + j;
            float val = 0.0f;
            if (n < DIM && k < DIM)
                val = (sec == 0) ? w[k * DIM + n] : w[n * DIM + k];
            v[j] = f2bf(val);
        }
        *(uint4*)(o + (size_t)f * 8) = *(uint4*)v;
        return;
    }
    idx -= PS_D;
    if (idx < PS_E) {
        int k = idx / DIM, n = idx % DIM;
        const float* ar = (k < DIM) ? (lw2 + (size_t)k * DIM) : b2;
        const float* br = wih + (size_t)n * DIM;
        float s0 = 0.f, s1 = 0.f, s2 = 0.f, s3 = 0.f;
        #pragma unroll 5
        for (int q = 0; q < DIM; q += 4) {
            float4 a = *(const float4*)(ar + q);
            float4 b = *(const float4*)(br + q);
            s0 += a.x * b.x; s1 += a.y * b.y; s2 += a.z * b.z; s3 += a.w * b.w;
        }
        float s = (s0 + s1) + (s2 + s3);
        if (k == DIM) s += b_ih[n] + b_hh[n];
        Mt[idx] = s;
    }
}

// ---------------------------------------------------------------- scan (padded degrees)
__global__ __launch_bounds__(256) void scanA(const int* __restrict__ degi,
                                             int* __restrict__ pos,
                                             int* __restrict__ bsum) {
    __shared__ int tmp[256];
    int t = threadIdx.x;
    int g = blockIdx.x * 256 + t;
    int d = (g < N_NODES) ? degi[g] : 0;
    int v = (d + 3) & ~3;                    // padded degree (0 stays 0)
    tmp[t] = v;
    __syncthreads();
    for (int off = 1; off < 256; off <<= 1) {
        int xv = (t >= off) ? tmp[t - off] : 0;
        __syncthreads();
        tmp[t] += xv;
        __syncthreads();
    }
    if (g < N_NODES) pos[g] = tmp[t] - v;
    if (t == 255) bsum[blockIdx.x] = tmp[255];
}

__global__ __launch_bounds__(256) void scanC2(int* __restrict__ pos,
                                              const int* __restrict__ bsum) {
    __shared__ int tmp[256];
    __shared__ int excl[256];
    int t = threadIdx.x;
    int v = (t < NB_SCAN) ? bsum[t] : 0;
    tmp[t] = v;
    __syncthreads();
    for (int off = 1; off < 256; off <<= 1) {
        int xv = (t >= off) ? tmp[t - off] : 0;
        __syncthreads();
        tmp[t] += xv;
        __syncthreads();
    }
    excl[t] = tmp[t] - v;
    __syncthreads();
    int add = excl[blockIdx.x];
    int g = blockIdx.x * 256 + t;
    if (g < N_NODES) pos[g] += add;
}

// ---------------------------------------------------------------- mega-prep 2:
#define M2_A (N_EDGES / 8)
#define M2_B N_NODES
#define M2_C (NFRAG8 + KPN)
#define M2_TOTAL (M2_A + M2_B + M2_C)

__global__ __launch_bounds__(256) void mega2(
        const int* __restrict__ src, const int* __restrict__ dst,
        const int* __restrict__ et, const int* __restrict__ rank,
        const int* __restrict__ pos, const int* __restrict__ degi,
        int* __restrict__ se,
        const float* __restrict__ Mt, unsigned short* __restrict__ Mf,
        float* __restrict__ biasv) {
    int idx = blockIdx.x * blockDim.x + threadIdx.x;
    if (idx < M2_A) {                                   // --- fill, no atomics
        int e0 = idx * 8;
        int4 da = *(const int4*)(dst + e0);
        int4 db = *(const int4*)(dst + e0 + 4);
        int4 sa = *(const int4*)(src + e0);
        int4 sb = *(const int4*)(src + e0 + 4);
        int4 ta = *(const int4*)(et + e0);
        int4 tb = *(const int4*)(et + e0 + 4);
        int4 ra = *(const int4*)(rank + e0);
        int4 rb = *(const int4*)(rank + e0 + 4);
        se[pos[da.x] + ra.x] = sa.x | (ta.x << 16);
        se[pos[da.y] + ra.y] = sa.y | (ta.y << 16);
        se[pos[da.z] + ra.z] = sa.z | (ta.z << 16);
        se[pos[da.w] + ra.w] = sa.w | (ta.w << 16);
        se[pos[db.x] + rb.x] = sb.x | (tb.x << 16);
        se[pos[db.y] + rb.y] = sb.y | (tb.y << 16);
        se[pos[db.z] + rb.z] = sb.z | (tb.z << 16);
        se[pos[db.w] + rb.w] = sb.w | (tb.w << 16);
        return;
    }
    idx -= M2_A;
    if (idx < M2_B) {                                   // --- pad fill
        int d = degi[idx];
        if (d > 0) {
            int dp = (d + 3) & ~3;
            int start = pos[idx];
            for (int j = d; j < dp; ++j) se[start + j] = DUMMYROW;
        }
        return;
    }
    idx -= M2_B;
    if (idx < NFRAG8) {
        int l = idx & 63;
        int ks = (idx >> 6) % 14;
        int nt = idx / (14 * 64);
        int n  = nt * 32 + (l & 31);
        int k0 = ks * 16 + (l >> 5) * 8;
        unsigned short v[8];
        #pragma unroll
        for (int j = 0; j < 8; ++j) {
            int k = k0 + j;
            v[j] = f2bf((n < DIM && k < DIM) ? Mt[k * DIM + n] : 0.0f);
        }
        *(uint4*)(Mf + (size_t)idx * 8) = *(uint4*)v;
    } else if (idx < NFRAG8 + KPN) {
        int n = idx - NFRAG8;
        biasv[n] = (n < DIM) ? Mt[DIM * DIM + n] : 0.0f;
    }
}

// ---------------------------------------------------------------- gather: 3-group (4-edge) rotation, ~12 edges in flight
#define GL(QQ, XU, WU)                                                  \
    { int p_ = uread(sv, (QQ)); int s_ = p_ & 0xffff; int r_ = p_ >> 16;\
      XU = *(const uint2*)(x  + (size_t)s_ * KPAD + xoff);              \
      WU = *(const uint4*)(wb + (size_t)r_ * (NBLK * 4) + woff); }

#define GL4(Q0, XA, WA)                                                 \
    { GL((Q0),     XA##0, WA##0); GL((Q0) + 1, XA##1, WA##1);           \
      GL((Q0) + 2, XA##2, WA##2); GL((Q0) + 3, XA##3, WA##3); }

#define CMP16(XA, WA)                                                   \
    { CMP4(XA##0, WA##0); CMP4(XA##1, WA##1);                           \
      CMP4(XA##2, WA##2); CMP4(XA##3, WA##3); }

__global__ __launch_bounds__(256) void gatherB(
        const unsigned short* __restrict__ x,    // [NROWPAD][KPAD] bf16
        const int*   __restrict__ se,            // packed (src | et<<16), padded CSR
        const int*   __restrict__ pstart,        // padded segment start
        const int*   __restrict__ degi,
        const unsigned short* __restrict__ wb,   // [R][NBLK][4] bf16 (column pairs)
        unsigned short* __restrict__ agg) {      // [NROWPAD][KPAD] bf16
    int node = (blockIdx.x * blockDim.x + threadIdx.x) >> 6;
    int lane = threadIdx.x & 63;
    if (node >= N_NODES) return;
    int deg = __builtin_amdgcn_readfirstlane(degi[node]);
    const bool act = (lane < 50);
    int cl   = act ? lane : 49;
    int xoff = 4 * cl;
    int woff = 8 * cl;

    if (deg == 0) {
        if (lane < 56) *(uint2*)(agg + (size_t)node * KPAD + 4 * lane) = make_uint2(0u, 0u);
        return;
    }
    int start = __builtin_amdgcn_readfirstlane(pstart[node]);
    int degp  = (deg + 3) & ~3;

    float m0 = 0.f, m1 = 0.f, m2 = 0.f, m3 = 0.f;

    for (int base = 0; base < degp; base += 64) {
        int cnt = degp - base; if (cnt > 64) cnt = 64;   // multiple of 4, >= 4
        int sv = se[start + base + (lane < cnt ? lane : cnt - 1)];

        uint2 XA0, XA1, XA2, XA3, XB0, XB1, XB2, XB3, XC0, XC1, XC2, XC3;
        uint4 WA0, WA1, WA2, WA3, WB0, WB1, WB2, WB3, WC0, WC1, WC2, WC3;

        GL4(0, XA, WA);
        if (4 < cnt) GL4(4, XB, WB);

        for (int q = 0; q < cnt; q += 12) {
            if (q + 8  < cnt) GL4(q + 8, XC, WC);
            CMP16(XA, WA);
            if (q + 12 < cnt) GL4(q + 12, XA, WA);
            if (q + 4  < cnt) CMP16(XB, WB);
            if (q + 16 < cnt) GL4(q + 16, XB, WB);
            if (q + 8  < cnt) CMP16(XC, WC);
        }
    }
    float nrm = 1.0f / (float)deg;
    uint2 ov = make_uint2(0u, 0u);
    if (act) {
        ov.x = (unsigned)f2bf(m0 * nrm) | ((unsigned)f2bf(m1 * nrm) << 16);
        ov.y = (unsigned)f2bf(m2 * nrm) | ((unsigned)f2bf(m3 * nrm) << 16);
    }
    if (lane < 56) *(uint2*)(agg + (size_t)node * KPAD + 4 * lane) = ov;
}

// ---------------------------------------------------------------- GEMM1: hb = bf16(tanh(agg1 + x@loop_w1 + b1))
__global__ __launch_bounds__(256) void gemm1_kernel(
        unsigned short* xb_hb,
        const unsigned short* __restrict__ agg1,  // [NROWPAD][KPAD] bf16
        const float* __restrict__ b1,
        const unsigned short* __restrict__ w1f) {
    __shared__ __align__(16) unsigned short s_a[32 * KPN];
    int row0 = blockIdx.x * 32;
    int tid = threadIdx.x;
    for (int i = tid; i < 32 * 32; i += 256) {
        int rr = i >> 5, ch = i & 31;
        uint4 v = {0, 0, 0, 0};
        if (ch < 28) v = *(const uint4*)(xb_hb + (size_t)(row0 + rr) * KPAD + ch * 8);
        *(uint4*)((char*)s_a + SWZ5(rr, ch * 16)) = v;
    }
    __syncthreads();

    int l = tid & 63, wv = tid >> 6;
    int rl = l & 31, hl = l >> 5;
    int ntlo = wv * 2;
    const unsigned short* wb = w1f + (size_t)(ntlo * 14) * 512 + l * 8;

    f32x16 acc0 = {}, acc1 = {};
    short8 aC  = *(const short8*)((const char*)s_a + SWZ5(rl, (hl * 8) * 2));
    short8 b0C = *(const short8*)(wb);
    short8 b1C = *(const short8*)(wb + 14 * 512);
    #pragma unroll
    for (int ks = 0; ks < 13; ++ks) {
        short8 aN = {}, b0N = {}, b1N = {};
        if (ks < 12) {
            aN  = *(const short8*)((const char*)s_a + SWZ5(rl, ((ks + 1) * 16 + hl * 8) * 2));
            b0N = *(const short8*)(wb + (ks + 1) * 512);
            b1N = *(const short8*)(wb + 14 * 512 + (ks + 1) * 512);
        }
        acc0 = __builtin_amdgcn_mfma_f32_32x32x16_bf16(aC, b0C, acc0, 0, 0, 0);
        acc1 = __builtin_amdgcn_mfma_f32_32x32x16_bf16(aC, b1C, acc1, 0, 0, 0);
        aC = aN; b0C = b0N; b1C = b1N;
    }
    __syncthreads();   // all tile reads done before in-place overwrite

    #pragma unroll
    for (int t = 0; t < 2; ++t) {
        f32x16 ac = t ? acc1 : acc0;
        int gc = (ntlo + t) * 32 + rl;
        if (gc >= KPAD) continue;
        float bias = (gc < DIM) ? b1[gc] : 0.0f;
        #pragma unroll
        for (int r = 0; r < 16; ++r) {
            int gr = row0 + (r & 3) + 8 * (r >> 2) + 4 * hl;
            float v = 0.0f;
            if (gc < DIM && gr < N_NODES)
                v = ac[r] + b2f(agg1[(size_t)gr * KPAD + gc]) + bias;
            xb_hb[(size_t)gr * KPAD + gc] = f2bf(tanh_fast(v));
        }
    }
}

// ---------------------------------------------------------------- GEMM2 single-phase, K-halved LDS (24KB):
__global__ __launch_bounds__(256) void gemm2_kernel(
        const unsigned short* __restrict__ hb,
        const unsigned short* __restrict__ aggp,  // [NROWPAD][KPAD] bf16
        const unsigned short* __restrict__ h0b,   // [NROWPAD][KPAD] bf16
        const unsigned short* __restrict__ Mf,
        const unsigned short* __restrict__ wihf,
        const unsigned short* __restrict__ whhf,
        const float* __restrict__ biasv,
        float* __restrict__ out) {
    __shared__ __align__(16) unsigned short s_h[32 * 128];   // 8KB each, 256B-stride rows
    __shared__ __align__(16) unsigned short s_g[32 * 128];
    __shared__ __align__(16) unsigned short s_e[32 * 128];
    int row0 = blockIdx.x * 32;
    int tid = threadIdx.x;
    int l = tid & 63, wv = tid >> 6;
    int rl = l & 31, hl = l >> 5;
    int ntlo = wv * 2;
    const unsigned short* pm = Mf   + (size_t)(ntlo * 14) * 512 + l * 8;
    const unsigned short* pi = wihf + (size_t)(ntlo * 14) * 512 + l * 8;
    const unsigned short* ph = whhf + (size_t)(ntlo * 14) * 512 + l * 8;

    f32x16 a0 = {}, a1 = {};

    for (int half = 0; half < 2; ++half) {
        for (int i = tid; i < 32 * 14; i += 256) {
            int rr = i / 14, ch = i % 14;
            size_t off = (size_t)(row0 + rr) * KPAD + (half * 14 + ch) * 8;
            unsigned sw = SWZH(rr, ch * 16);
            *(uint4*)((char*)s_h + sw) = *(const uint4*)(hb   + off);
            *(uint4*)((char*)s_g + sw) = *(const uint4*)(aggp + off);
            *(uint4*)((char*)s_e + sw) = *(const uint4*)(h0b  + off);
        }
        __syncthreads();

        const int kbase = half * 7;
        unsigned off0 = SWZH(rl, (hl * 8) * 2);
        short8 hC  = *(const short8*)((const char*)s_h + off0);
        short8 gC  = *(const short8*)((const char*)s_g + off0);
        short8 eC  = *(const short8*)((const char*)s_e + off0);
        short8 m0C = *(const short8*)(pm + kbase * 512);
        short8 m1C = *(const short8*)(pm + 14 * 512 + kbase * 512);
        short8 i0C = *(const short8*)(pi + kbase * 512);
        short8 i1C = *(const short8*)(pi + 14 * 512 + kbase * 512);
        short8 h0C = *(const short8*)(ph + kbase * 512);
        short8 h1C = *(const short8*)(ph + 14 * 512 + kbase * 512);
        #pragma unroll
        for (int ks = 0; ks < 7; ++ks) {
            short8 hN = {}, gN = {}, eN = {};
            short8 m0N = {}, m1N = {}, i0N = {}, i1N = {}, h0N = {}, h1N = {};
            if (ks < 6) {
                unsigned off = SWZH(rl, ((ks + 1) * 16 + hl * 8) * 2);
                hN  = *(const short8*)((const char*)s_h + off);
                gN  = *(const short8*)((const char*)s_g + off);
                eN  = *(const short8*)((const char*)s_e + off);
                int kg = kbase + ks + 1;
                m0N = *(const short8*)(pm + kg * 512);
                m1N = *(const short8*)(pm + 14 * 512 + kg * 512);
                i0N = *(const short8*)(pi + kg * 512);
                i1N = *(const short8*)(pi + 14 * 512 + kg * 512);
                h0N = *(const short8*)(ph + kg * 512);
                h1N = *(const short8*)(ph + 14 * 512 + kg * 512);
            }
            a0 = __builtin_amdgcn_mfma_f32_32x32x16_bf16(hC, m0C, a0, 0, 0, 0);
            a1 = __builtin_amdgcn_mfma_f32_32x32x16_bf16(hC, m1C, a1, 0, 0, 0);
            a0 = __builtin_amdgcn_mfma_f32_32x32x16_bf16(gC, i0C, a0, 0, 0, 0);
            a1 = __builtin_amdgcn_mfma_f32_32x32x16_bf16(gC, i1C, a1, 0, 0, 0);
            a0 = __builtin_amdgcn_mfma_f32_32x32x16_bf16(eC, h0C, a0, 0, 0, 0);
            a1 = __builtin_amdgcn_mfma_f32_32x32x16_bf16(eC, h1C, a1, 0, 0, 0);
            hC = hN; gC = gN; eC = eN;
            m0C = m0N; m1C = m1N; i0C = i0N; i1C = i1N; h0C = h0N; h1C = h1N;
        }
        __syncthreads();   // MFMA reads done before restage
    }

    #pragma unroll
    for (int t = 0; t < 2; ++t) {
        f32x16 oc = t ? a1 : a0;
        int gc = (ntlo + t) * 32 + rl;
        if (gc >= DIM) continue;
        float bias = biasv[gc];
        #pragma unroll
        for (int r = 0; r < 16; ++r) {
            int gr = row0 + (r & 3) + 8 * (r >> 2) + 4 * hl;
            if (gr < N_NODES)
                out[(size_t)gr * DIM + gc] = tanh_fast(oc[r] + bias);
        }
    }
}

// ---------------------------------------------------------------- launch
extern "C" void kernel_launch(void* const* d_in, const int* in_sizes, int n_in,
                              void* d_out, int out_size, void* d_ws, size_t ws_size,
                              hipStream_t stream) {
    const float* node_feat = (const float*)d_in[0];
    const float* dyn_emb   = (const float*)d_in[1];
    const int*   src       = (const int*)  d_in[2];
    const int*   dst       = (const int*)  d_in[3];
    const int*   etypes    = (const int*)  d_in[4];
    const float* w1        = (const float*)d_in[5];
    const float* loop_w1   = (const float*)d_in[6];
    const float* b1        = (const float*)d_in[7];
    const float* w2        = (const float*)d_in[8];
    const float* loop_w2   = (const float*)d_in[9];
    const float* b2        = (const float*)d_in[10];
    const float* W_ih      = (const float*)d_in[11];
    const float* W_hh      = (const float*)d_in[12];
    const float* b_ih      = (const float*)d_in[13];
    const float* b_hh      = (const float*)d_in[14];
    float* out = (float*)d_out;

    // workspace layout (~76 MB)
    int*   degi = (int*)d_ws;                          // 51200
    int*   pos  = degi + 51200;                        // 51200 (padded starts)
    int*   bsum = pos  + 51200;                        // 256
    int*   rank = bsum + 256;                          // N_EDGES ints (3.2 MB)
    int*   se   = rank + N_EDGES;                      // EPADMAX ints (3.8 MB)
    unsigned short* aggp = (unsigned short*)(se + EPADMAX);    // NROWPAD*KPAD bf16 (22.4 MB)
    unsigned short* hb   = aggp + (size_t)NROWPAD * KPAD;      // 22.4 MB — ALSO xb
    unsigned short* h0b  = hb   + (size_t)NROWPAD * KPAD;      // 22.4 MB
    unsigned short* w1f  = h0b  + (size_t)NROWPAD * KPAD;      // NFRAG8*8 each
    unsigned short* wihf = w1f  + (size_t)NFRAG8 * 8;
    unsigned short* whhf = wihf + (size_t)NFRAG8 * 8;
    unsigned short* Mf   = whhf + (size_t)NFRAG8 * 8;
    unsigned short* w1b  = Mf   + (size_t)NFRAG8 * 8;          // NRELS*NBLK*4
    unsigned short* w2b  = w1b  + (size_t)NRELS * NBLK * 4;
    float* biasv = (float*)(w2b + (size_t)NRELS * NBLK * 4);   // KPN floats
    float* Mt    = biasv + KPN;                                // (DIM+1)*DIM floats

    hipMemsetAsync(degi, 0, 51200 * sizeof(int), stream);

    deg_rank<<<(N_EDGES / 8 + 255) / 256, 256, 0, stream>>>(dst, degi, rank);
    prep_feat2<<<(2 * NROWPAD * 28 + 255) / 256, 256, 0, stream>>>(
        node_feat, dyn_emb, hb, h0b);
    prep_small<<<(PS_TOTAL + 255) / 256, 256, 0, stream>>>(
        w1, w2, w1b, w2b, loop_w1, W_ih, W_hh, w1f, wihf, whhf,
        loop_w2, b2, b_ih, b_hh, Mt);

    scanA<<<NB_SCAN, 256, 0, stream>>>(degi, pos, bsum);
    scanC2<<<NB_SCAN, 256, 0, stream>>>(pos, bsum);

    mega2<<<(M2_TOTAL + 255) / 256, 256, 0, stream>>>(
        src, dst, etypes, rank, pos, degi, se, Mt, Mf, biasv);

    // ---- layer 1 (gather reads xb=hb; gemm1 overwrites it in place with h)
    gatherB<<<(N_NODES * 64 + 255) / 256, 256, 0, stream>>>(
        hb, se, pos, degi, w1b, aggp);
    gemm1_kernel<<<(N_NODES + 31) / 32, 256, 0, stream>>>(
        hb, aggp, b1, w1f);

    // ---- layer 2
    gatherB<<<(N_NODES * 64 + 255) / 256, 256, 0, stream>>>(
        hb, se, pos, degi, w2b, aggp);

    // ---- fused layer-2 dense + RNN cell (single phase via M = w2 @ W_ih^T)
    gemm2_kernel<<<(N_NODES + 31) / 32, 256, 0, stream>>>(
        hb, aggp, h0b, Mf, wihf, whhf, biasv, out);
}

// Round 19
// 292.338 us; speedup vs baseline: 1.0417x; 1.0417x over previous
//
#include <hip/hip_runtime.h>

#define N_NODES 50000
#define N_EDGES 800000
#define DIM     200
#define NBLK    100   // B blocks of S=2
#define NRELS   230
#define NB_SCAN 196   // ceil(N_NODES/256)
#define KPAD    224   // feature-row stride (bf16 buffers)
#define KPN     256   // gemm output-column pad (8 nt of 32)
#define NROWPAD 50048
#define NFRAG8  (8 * 14 * 64)   // fragment-packed weights: 8 nt x 14 ks x 64 lanes (x8 bf16)
#define EPADMAX (N_EDGES + 3 * N_NODES + 16)   // padded CSR capacity
#define DUMMYROW 50000                          // zero bf16 row for pad edges

typedef __attribute__((ext_vector_type(8)))  short short8;
typedef __attribute__((ext_vector_type(16))) float f32x16;

__device__ __forceinline__ unsigned short f2bf(float f) {
    unsigned u = __float_as_uint(f);
    u += 0x7fffu + ((u >> 16) & 1u);        // RNE (inputs finite)
    return (unsigned short)(u >> 16);
}

__device__ __forceinline__ float bflo(unsigned u) { return __uint_as_float(u << 16); }
__device__ __forceinline__ float bfhi(unsigned u) { return __uint_as_float(u & 0xffff0000u); }
__device__ __forceinline__ float b2f(unsigned short u) { return __uint_as_float((unsigned)u << 16); }

__device__ __forceinline__ float tanh_fast(float x) {
    float xa = fminf(fmaxf(x, -15.0f), 15.0f);
    float e = __expf(2.0f * xa);
    return (e - 1.0f) / (e + 1.0f);
}

__device__ __forceinline__ int uread(int v, int l) {
    return __builtin_amdgcn_readlane(v, l);
}

// ---- bf16 dot2: 1 instruction for a0*b0+a1*b1+c when available
#if __has_builtin(__builtin_amdgcn_fdot2_f32_bf16)
typedef __bf16 bf16x2 __attribute__((ext_vector_type(2)));
__device__ __forceinline__ float dot2bf(unsigned a, unsigned b, float c) {
    return __builtin_amdgcn_fdot2_f32_bf16(
        __builtin_bit_cast(bf16x2, a), __builtin_bit_cast(bf16x2, b), c, false);
}
#define CMP4(XU, WU)                                                    \
    { m0 = dot2bf(XU.x, WU.x, m0); m1 = dot2bf(XU.x, WU.y, m1);         \
      m2 = dot2bf(XU.y, WU.z, m2); m3 = dot2bf(XU.y, WU.w, m3); }
#else
#define CMP4(XU, WU)                                                    \
    { float x0 = bflo(XU.x), x1 = bfhi(XU.x);                           \
      float x2 = bflo(XU.y), x3 = bfhi(XU.y);                           \
      m0 += x0 * bflo(WU.x) + x1 * bfhi(WU.x);                          \
      m1 += x0 * bflo(WU.y) + x1 * bfhi(WU.y);                          \
      m2 += x2 * bflo(WU.z) + x3 * bfhi(WU.z);                          \
      m3 += x2 * bflo(WU.w) + x3 * bfhi(WU.w); }
#endif

// LDS swizzles: 512B-stride rows (gemm1) and 256B-stride rows (gemm2 halves)
#define SWZ5(rr, off) ((unsigned)((rr) * 512 + (off)) ^ ((unsigned)((rr) & 15) << 4))
#define SWZH(rr, off) ((unsigned)((rr) * 256 + (off)) ^ ((unsigned)((rr) & 15) << 4))

// ---------------------------------------------------------------- degree + rank (ONE atomic pass)
__global__ void deg_rank(const int* __restrict__ dst, int* __restrict__ degi,
                         int* __restrict__ rank) {
    int idx = blockIdx.x * blockDim.x + threadIdx.x;
    if (idx >= N_EDGES / 8) return;
    int e0 = idx * 8;
    int4 da = *(const int4*)(dst + e0);
    int4 db = *(const int4*)(dst + e0 + 4);
    int r0 = atomicAdd(&degi[da.x], 1);
    int r1 = atomicAdd(&degi[da.y], 1);
    int r2 = atomicAdd(&degi[da.z], 1);
    int r3 = atomicAdd(&degi[da.w], 1);
    int r4 = atomicAdd(&degi[db.x], 1);
    int r5 = atomicAdd(&degi[db.y], 1);
    int r6 = atomicAdd(&degi[db.z], 1);
    int r7 = atomicAdd(&degi[db.w], 1);
    *(int4*)(rank + e0)     = make_int4(r0, r1, r2, r3);
    *(int4*)(rank + e0 + 4) = make_int4(r4, r5, r6, r7);
}

// ---------------------------------------------------------------- feature prep, vectorized
__global__ void prep_feat2(const float* __restrict__ x, const float* __restrict__ de,
                           unsigned short* __restrict__ xb, unsigned short* __restrict__ h0b) {
    const int HALF = NROWPAD * 28;
    int idx = blockIdx.x * blockDim.x + threadIdx.x;
    if (idx >= 2 * HALF) return;
    const float* src = (idx < HALF) ? x : de;
    unsigned short* o = (idx < HALF) ? xb : h0b;
    int j = (idx < HALF) ? idx : idx - HALF;
    int row = j / 28, c8 = j % 28;
    uint4 pk = {0, 0, 0, 0};
    if (row < N_NODES && c8 < 25) {
        const float* p = src + (size_t)row * DIM + c8 * 8;
        float4 a = *(const float4*)p;
        float4 b = *(const float4*)(p + 4);
        pk.x = (unsigned)f2bf(a.x) | ((unsigned)f2bf(a.y) << 16);
        pk.y = (unsigned)f2bf(a.z) | ((unsigned)f2bf(a.w) << 16);
        pk.z = (unsigned)f2bf(b.x) | ((unsigned)f2bf(b.y) << 16);
        pk.w = (unsigned)f2bf(b.z) | ((unsigned)f2bf(b.w) << 16);
    }
    *(uint4*)(o + (size_t)j * 8) = pk;
}

// ---------------------------------------------------------------- small weight preps:
#define PS_C (2 * NRELS * NBLK)
#define PS_D (3 * NFRAG8)
#define PS_E ((DIM + 1) * DIM)
#define PS_TOTAL (PS_C + PS_D + PS_E)

__global__ __launch_bounds__(256) void prep_small(
        const float* __restrict__ w1, const float* __restrict__ w2,
        unsigned short* __restrict__ w1b, unsigned short* __restrict__ w2b,
        const float* __restrict__ lw1, const float* __restrict__ wih,
        const float* __restrict__ whh,
        unsigned short* __restrict__ w1f, unsigned short* __restrict__ wihf,
        unsigned short* __restrict__ whhf,
        const float* __restrict__ lw2, const float* __restrict__ b2,
        const float* __restrict__ b_ih, const float* __restrict__ b_hh,
        float* __restrict__ Mt) {
    int idx = blockIdx.x * blockDim.x + threadIdx.x;
    if (idx < PS_C) {
        const int HALF = NRELS * NBLK;
        const float* w = (idx < HALF) ? w1 : w2;
        unsigned short* o = (idx < HALF) ? w1b : w2b;
        int j = (idx < HALF) ? idx : idx - HALF;
        float4 v = *(const float4*)(w + (size_t)j * 4);  // w00,w01,w10,w11
        unsigned c0 = (unsigned)f2bf(v.x) | ((unsigned)f2bf(v.z) << 16);
        unsigned c1 = (unsigned)f2bf(v.y) | ((unsigned)f2bf(v.w) << 16);
        *(uint2*)(o + (size_t)j * 4) = make_uint2(c0, c1);
        return;
    }
    idx -= PS_C;
    if (idx < PS_D) {
        int sec = idx / NFRAG8, f = idx % NFRAG8;
        const float* w = (sec == 0) ? lw1 : (sec == 1) ? wih : whh;
        unsigned short* o = (sec == 0) ? w1f : (sec == 1) ? wihf : whhf;
        int l = f & 63;
        int ks = (f >> 6) % 14;
        int nt = f / (14 * 64);
        int n  = nt * 32 + (l & 31);
        int k0 = ks * 16 + (l >> 5) * 8;
        unsigned short v[8];
        #pragma unroll
        for (int j = 0; j < 8; ++j) {
            int k = k0 + j;
            float val = 0.0f;
            if (n < DIM && k < DIM)
                val = (sec == 0) ? w[k * DIM + n] : w[n * DIM + k];
            v[j] = f2bf(val);
        }
        *(uint4*)(o + (size_t)f * 8) = *(uint4*)v;
        return;
    }
    idx -= PS_D;
    if (idx < PS_E) {
        int k = idx / DIM, n = idx % DIM;
        const float* ar = (k < DIM) ? (lw2 + (size_t)k * DIM) : b2;
        const float* br = wih + (size_t)n * DIM;
        float s0 = 0.f, s1 = 0.f, s2 = 0.f, s3 = 0.f;
        #pragma unroll 5
        for (int q = 0; q < DIM; q += 4) {
            float4 a = *(const float4*)(ar + q);
            float4 b = *(const float4*)(br + q);
            s0 += a.x * b.x; s1 += a.y * b.y; s2 += a.z * b.z; s3 += a.w * b.w;
        }
        float s = (s0 + s1) + (s2 + s3);
        if (k == DIM) s += b_ih[n] + b_hh[n];
        Mt[idx] = s;
    }
}

// ---------------------------------------------------------------- scan (padded degrees)
__global__ __launch_bounds__(256) void scanA(const int* __restrict__ degi,
                                             int* __restrict__ pos,
                                             int* __restrict__ bsum) {
    __shared__ int tmp[256];
    int t = threadIdx.x;
    int g = blockIdx.x * 256 + t;
    int d = (g < N_NODES) ? degi[g] : 0;
    int v = (d + 3) & ~3;                    // padded degree (0 stays 0)
    tmp[t] = v;
    __syncthreads();
    for (int off = 1; off < 256; off <<= 1) {
        int xv = (t >= off) ? tmp[t - off] : 0;
        __syncthreads();
        tmp[t] += xv;
        __syncthreads();
    }
    if (g < N_NODES) pos[g] = tmp[t] - v;
    if (t == 255) bsum[blockIdx.x] = tmp[255];
}

__global__ __launch_bounds__(256) void scanC2(int* __restrict__ pos,
                                              const int* __restrict__ bsum) {
    __shared__ int tmp[256];
    __shared__ int excl[256];
    int t = threadIdx.x;
    int v = (t < NB_SCAN) ? bsum[t] : 0;
    tmp[t] = v;
    __syncthreads();
    for (int off = 1; off < 256; off <<= 1) {
        int xv = (t >= off) ? tmp[t - off] : 0;
        __syncthreads();
        tmp[t] += xv;
        __syncthreads();
    }
    excl[t] = tmp[t] - v;
    __syncthreads();
    int add = excl[blockIdx.x];
    int g = blockIdx.x * 256 + t;
    if (g < N_NODES) pos[g] += add;
}

// ---------------------------------------------------------------- mega-prep 2:
#define M2_A (N_EDGES / 8)
#define M2_B N_NODES
#define M2_C (NFRAG8 + KPN)
#define M2_TOTAL (M2_A + M2_B + M2_C)

__global__ __launch_bounds__(256) void mega2(
        const int* __restrict__ src, const int* __restrict__ dst,
        const int* __restrict__ et, const int* __restrict__ rank,
        const int* __restrict__ pos, const int* __restrict__ degi,
        int* __restrict__ se,
        const float* __restrict__ Mt, unsigned short* __restrict__ Mf,
        float* __restrict__ biasv) {
    int idx = blockIdx.x * blockDim.x + threadIdx.x;
    if (idx < M2_A) {                                   // --- fill, no atomics
        int e0 = idx * 8;
        int4 da = *(const int4*)(dst + e0);
        int4 db = *(const int4*)(dst + e0 + 4);
        int4 sa = *(const int4*)(src + e0);
        int4 sb = *(const int4*)(src + e0 + 4);
        int4 ta = *(const int4*)(et + e0);
        int4 tb = *(const int4*)(et + e0 + 4);
        int4 ra = *(const int4*)(rank + e0);
        int4 rb = *(const int4*)(rank + e0 + 4);
        se[pos[da.x] + ra.x] = sa.x | (ta.x << 16);
        se[pos[da.y] + ra.y] = sa.y | (ta.y << 16);
        se[pos[da.z] + ra.z] = sa.z | (ta.z << 16);
        se[pos[da.w] + ra.w] = sa.w | (ta.w << 16);
        se[pos[db.x] + rb.x] = sb.x | (tb.x << 16);
        se[pos[db.y] + rb.y] = sb.y | (tb.y << 16);
        se[pos[db.z] + rb.z] = sb.z | (tb.z << 16);
        se[pos[db.w] + rb.w] = sb.w | (tb.w << 16);
        return;
    }
    idx -= M2_A;
    if (idx < M2_B) {                                   // --- pad fill
        int d = degi[idx];
        if (d > 0) {
            int dp = (d + 3) & ~3;
            int start = pos[idx];
            for (int j = d; j < dp; ++j) se[start + j] = DUMMYROW;
        }
        return;
    }
    idx -= M2_B;
    if (idx < NFRAG8) {
        int l = idx & 63;
        int ks = (idx >> 6) % 14;
        int nt = idx / (14 * 64);
        int n  = nt * 32 + (l & 31);
        int k0 = ks * 16 + (l >> 5) * 8;
        unsigned short v[8];
        #pragma unroll
        for (int j = 0; j < 8; ++j) {
            int k = k0 + j;
            v[j] = f2bf((n < DIM && k < DIM) ? Mt[k * DIM + n] : 0.0f);
        }
        *(uint4*)(Mf + (size_t)idx * 8) = *(uint4*)v;
    } else if (idx < NFRAG8 + KPN) {
        int n = idx - NFRAG8;
        biasv[n] = (n < DIM) ? Mt[DIM * DIM + n] : 0.0f;
    }
}

// ---------------------------------------------------------------- gather: branch-free padded pipeline (R17 best)
#define GL(QQ, XU, WU)                                                  \
    { int p_ = uread(sv, (QQ)); int s_ = p_ & 0xffff; int r_ = p_ >> 16;\
      XU = *(const uint2*)(x  + (size_t)s_ * KPAD + xoff);              \
      WU = *(const uint4*)(wb + (size_t)r_ * (NBLK * 4) + woff); }

__global__ __launch_bounds__(256) void gatherB(
        const unsigned short* __restrict__ x,    // [NROWPAD][KPAD] bf16
        const int*   __restrict__ se,            // packed (src | et<<16), padded CSR
        const int*   __restrict__ pstart,        // padded segment start
        const int*   __restrict__ degi,
        const unsigned short* __restrict__ wb,   // [R][NBLK][4] bf16 (column pairs)
        unsigned short* __restrict__ agg) {      // [NROWPAD][KPAD] bf16
    int node = (blockIdx.x * blockDim.x + threadIdx.x) >> 6;
    int lane = threadIdx.x & 63;
    if (node >= N_NODES) return;
    int deg = __builtin_amdgcn_readfirstlane(degi[node]);
    const bool act = (lane < 50);
    int cl   = act ? lane : 49;
    int xoff = 4 * cl;
    int woff = 8 * cl;

    if (deg == 0) {
        if (lane < 56) *(uint2*)(agg + (size_t)node * KPAD + 4 * lane) = make_uint2(0u, 0u);
        return;
    }
    int start = __builtin_amdgcn_readfirstlane(pstart[node]);
    int degp  = (deg + 3) & ~3;

    float m0 = 0.f, m1 = 0.f, m2 = 0.f, m3 = 0.f;

    for (int base = 0; base < degp; base += 64) {
        int cnt = degp - base; if (cnt > 64) cnt = 64;   // multiple of 4, >= 4
        int sv = se[start + base + (lane < cnt ? lane : cnt - 1)];

        uint2 X0, X1, X2, X3, Y0, Y1, Y2, Y3;
        uint4 W0, W1, W2, W3, V0, V1, V2, V3;
        GL(0, X0, W0); GL(1, X1, W1); GL(2, X2, W2); GL(3, X3, W3);

        for (int q = 0; q < cnt; q += 8) {
            bool l1 = (q + 4 < cnt);
            if (l1) { GL(q + 4, Y0, V0); GL(q + 5, Y1, V1); GL(q + 6, Y2, V2); GL(q + 7, Y3, V3); }
            CMP4(X0, W0); CMP4(X1, W1); CMP4(X2, W2); CMP4(X3, W3);
            if (!l1) break;
            bool l2 = (q + 8 < cnt);
            if (l2) { GL(q + 8, X0, W0); GL(q + 9, X1, W1); GL(q + 10, X2, W2); GL(q + 11, X3, W3); }
            CMP4(Y0, V0); CMP4(Y1, V1); CMP4(Y2, V2); CMP4(Y3, V3);
        }
    }
    float nrm = 1.0f / (float)deg;
    uint2 ov = make_uint2(0u, 0u);
    if (act) {
        ov.x = (unsigned)f2bf(m0 * nrm) | ((unsigned)f2bf(m1 * nrm) << 16);
        ov.y = (unsigned)f2bf(m2 * nrm) | ((unsigned)f2bf(m3 * nrm) << 16);
    }
    if (lane < 56) *(uint2*)(agg + (size_t)node * KPAD + 4 * lane) = ov;
}

// ---------------------------------------------------------------- GEMM1: hb = bf16(tanh(agg1 + x@loop_w1 + b1))
__global__ __launch_bounds__(256) void gemm1_kernel(
        unsigned short* xb_hb,
        const unsigned short* __restrict__ agg1,  // [NROWPAD][KPAD] bf16
        const float* __restrict__ b1,
        const unsigned short* __restrict__ w1f) {
    __shared__ __align__(16) unsigned short s_a[32 * KPN];
    int row0 = blockIdx.x * 32;
    int tid = threadIdx.x;
    for (int i = tid; i < 32 * 32; i += 256) {
        int rr = i >> 5, ch = i & 31;
        uint4 v = {0, 0, 0, 0};
        if (ch < 28) v = *(const uint4*)(xb_hb + (size_t)(row0 + rr) * KPAD + ch * 8);
        *(uint4*)((char*)s_a + SWZ5(rr, ch * 16)) = v;
    }
    __syncthreads();

    int l = tid & 63, wv = tid >> 6;
    int rl = l & 31, hl = l >> 5;
    int ntlo = wv * 2;
    const unsigned short* wb = w1f + (size_t)(ntlo * 14) * 512 + l * 8;

    f32x16 acc0 = {}, acc1 = {};
    short8 aC  = *(const short8*)((const char*)s_a + SWZ5(rl, (hl * 8) * 2));
    short8 b0C = *(const short8*)(wb);
    short8 b1C = *(const short8*)(wb + 14 * 512);
    #pragma unroll
    for (int ks = 0; ks < 13; ++ks) {
        short8 aN = {}, b0N = {}, b1N = {};
        if (ks < 12) {
            aN  = *(const short8*)((const char*)s_a + SWZ5(rl, ((ks + 1) * 16 + hl * 8) * 2));
            b0N = *(const short8*)(wb + (ks + 1) * 512);
            b1N = *(const short8*)(wb + 14 * 512 + (ks + 1) * 512);
        }
        acc0 = __builtin_amdgcn_mfma_f32_32x32x16_bf16(aC, b0C, acc0, 0, 0, 0);
        acc1 = __builtin_amdgcn_mfma_f32_32x32x16_bf16(aC, b1C, acc1, 0, 0, 0);
        aC = aN; b0C = b0N; b1C = b1N;
    }
    __syncthreads();   // all tile reads done before in-place overwrite

    #pragma unroll
    for (int t = 0; t < 2; ++t) {
        f32x16 ac = t ? acc1 : acc0;
        int gc = (ntlo + t) * 32 + rl;
        if (gc >= KPAD) continue;
        float bias = (gc < DIM) ? b1[gc] : 0.0f;
        #pragma unroll
        for (int r = 0; r < 16; ++r) {
            int gr = row0 + (r & 3) + 8 * (r >> 2) + 4 * hl;
            float v = 0.0f;
            if (gc < DIM && gr < N_NODES)
                v = ac[r] + b2f(agg1[(size_t)gr * KPAD + gc]) + bias;
            xb_hb[(size_t)gr * KPAD + gc] = f2bf(tanh_fast(v));
        }
    }
}

// ---------------------------------------------------------------- GEMM2 single-phase, K-halved LDS (24KB):
__global__ __launch_bounds__(256) void gemm2_kernel(
        const unsigned short* __restrict__ hb,
        const unsigned short* __restrict__ aggp,  // [NROWPAD][KPAD] bf16
        const unsigned short* __restrict__ h0b,   // [NROWPAD][KPAD] bf16
        const unsigned short* __restrict__ Mf,
        const unsigned short* __restrict__ wihf,
        const unsigned short* __restrict__ whhf,
        const float* __restrict__ biasv,
        float* __restrict__ out) {
    __shared__ __align__(16) unsigned short s_h[32 * 128];   // 8KB each, 256B-stride rows
    __shared__ __align__(16) unsigned short s_g[32 * 128];
    __shared__ __align__(16) unsigned short s_e[32 * 128];
    int row0 = blockIdx.x * 32;
    int tid = threadIdx.x;
    int l = tid & 63, wv = tid >> 6;
    int rl = l & 31, hl = l >> 5;
    int ntlo = wv * 2;
    const unsigned short* pm = Mf   + (size_t)(ntlo * 14) * 512 + l * 8;
    const unsigned short* pi = wihf + (size_t)(ntlo * 14) * 512 + l * 8;
    const unsigned short* ph = whhf + (size_t)(ntlo * 14) * 512 + l * 8;

    f32x16 a0 = {}, a1 = {};

    for (int half = 0; half < 2; ++half) {
        for (int i = tid; i < 32 * 14; i += 256) {
            int rr = i / 14, ch = i % 14;
            size_t off = (size_t)(row0 + rr) * KPAD + (half * 14 + ch) * 8;
            unsigned sw = SWZH(rr, ch * 16);
            *(uint4*)((char*)s_h + sw) = *(const uint4*)(hb   + off);
            *(uint4*)((char*)s_g + sw) = *(const uint4*)(aggp + off);
            *(uint4*)((char*)s_e + sw) = *(const uint4*)(h0b  + off);
        }
        __syncthreads();

        const int kbase = half * 7;
        unsigned off0 = SWZH(rl, (hl * 8) * 2);
        short8 hC  = *(const short8*)((const char*)s_h + off0);
        short8 gC  = *(const short8*)((const char*)s_g + off0);
        short8 eC  = *(const short8*)((const char*)s_e + off0);
        short8 m0C = *(const short8*)(pm + kbase * 512);
        short8 m1C = *(const short8*)(pm + 14 * 512 + kbase * 512);
        short8 i0C = *(const short8*)(pi + kbase * 512);
        short8 i1C = *(const short8*)(pi + 14 * 512 + kbase * 512);
        short8 h0C = *(const short8*)(ph + kbase * 512);
        short8 h1C = *(const short8*)(ph + 14 * 512 + kbase * 512);
        #pragma unroll
        for (int ks = 0; ks < 7; ++ks) {
            short8 hN = {}, gN = {}, eN = {};
            short8 m0N = {}, m1N = {}, i0N = {}, i1N = {}, h0N = {}, h1N = {};
            if (ks < 6) {
                unsigned off = SWZH(rl, ((ks + 1) * 16 + hl * 8) * 2);
                hN  = *(const short8*)((const char*)s_h + off);
                gN  = *(const short8*)((const char*)s_g + off);
                eN  = *(const short8*)((const char*)s_e + off);
                int kg = kbase + ks + 1;
                m0N = *(const short8*)(pm + kg * 512);
                m1N = *(const short8*)(pm + 14 * 512 + kg * 512);
                i0N = *(const short8*)(pi + kg * 512);
                i1N = *(const short8*)(pi + 14 * 512 + kg * 512);
                h0N = *(const short8*)(ph + kg * 512);
                h1N = *(const short8*)(ph + 14 * 512 + kg * 512);
            }
            a0 = __builtin_amdgcn_mfma_f32_32x32x16_bf16(hC, m0C, a0, 0, 0, 0);
            a1 = __builtin_amdgcn_mfma_f32_32x32x16_bf16(hC, m1C, a1, 0, 0, 0);
            a0 = __builtin_amdgcn_mfma_f32_32x32x16_bf16(gC, i0C, a0, 0, 0, 0);
            a1 = __builtin_amdgcn_mfma_f32_32x32x16_bf16(gC, i1C, a1, 0, 0, 0);
            a0 = __builtin_amdgcn_mfma_f32_32x32x16_bf16(eC, h0C, a0, 0, 0, 0);
            a1 = __builtin_amdgcn_mfma_f32_32x32x16_bf16(eC, h1C, a1, 0, 0, 0);
            hC = hN; gC = gN; eC = eN;
            m0C = m0N; m1C = m1N; i0C = i0N; i1C = i1N; h0C = h0N; h1C = h1N;
        }
        __syncthreads();   // MFMA reads done before restage
    }

    #pragma unroll
    for (int t = 0; t < 2; ++t) {
        f32x16 oc = t ? a1 : a0;
        int gc = (ntlo + t) * 32 + rl;
        if (gc >= DIM) continue;
        float bias = biasv[gc];
        #pragma unroll
        for (int r = 0; r < 16; ++r) {
            int gr = row0 + (r & 3) + 8 * (r >> 2) + 4 * hl;
            if (gr < N_NODES)
                out[(size_t)gr * DIM + gc] = tanh_fast(oc[r] + bias);
        }
    }
}

// ---------------------------------------------------------------- launch
extern "C" void kernel_launch(void* const* d_in, const int* in_sizes, int n_in,
                              void* d_out, int out_size, void* d_ws, size_t ws_size,
                              hipStream_t stream) {
    const float* node_feat = (const float*)d_in[0];
    const float* dyn_emb   = (const float*)d_in[1];
    const int*   src       = (const int*)  d_in[2];
    const int*   dst       = (const int*)  d_in[3];
    const int*   etypes    = (const int*)  d_in[4];
    const float* w1        = (const float*)d_in[5];
    const float* loop_w1   = (const float*)d_in[6];
    const float* b1        = (const float*)d_in[7];
    const float* w2        = (const float*)d_in[8];
    const float* loop_w2   = (const float*)d_in[9];
    const float* b2        = (const float*)d_in[10];
    const float* W_ih      = (const float*)d_in[11];
    const float* W_hh      = (const float*)d_in[12];
    const float* b_ih      = (const float*)d_in[13];
    const float* b_hh      = (const float*)d_in[14];
    float* out = (float*)d_out;

    // workspace layout (~76 MB)
    int*   degi = (int*)d_ws;                          // 51200
    int*   pos  = degi + 51200;                        // 51200 (padded starts)
    int*   bsum = pos  + 51200;                        // 256
    int*   rank = bsum + 256;                          // N_EDGES ints (3.2 MB)
    int*   se   = rank + N_EDGES;                      // EPADMAX ints (3.8 MB)
    unsigned short* aggp = (unsigned short*)(se + EPADMAX);    // NROWPAD*KPAD bf16 (22.4 MB)
    unsigned short* hb   = aggp + (size_t)NROWPAD * KPAD;      // 22.4 MB — ALSO xb
    unsigned short* h0b  = hb   + (size_t)NROWPAD * KPAD;      // 22.4 MB
    unsigned short* w1f  = h0b  + (size_t)NROWPAD * KPAD;      // NFRAG8*8 each
    unsigned short* wihf = w1f  + (size_t)NFRAG8 * 8;
    unsigned short* whhf = wihf + (size_t)NFRAG8 * 8;
    unsigned short* Mf   = whhf + (size_t)NFRAG8 * 8;
    unsigned short* w1b  = Mf   + (size_t)NFRAG8 * 8;          // NRELS*NBLK*4
    unsigned short* w2b  = w1b  + (size_t)NRELS * NBLK * 4;
    float* biasv = (float*)(w2b + (size_t)NRELS * NBLK * 4);   // KPN floats
    float* Mt    = biasv + KPN;                                // (DIM+1)*DIM floats

    hipMemsetAsync(degi, 0, 51200 * sizeof(int), stream);

    deg_rank<<<(N_EDGES / 8 + 255) / 256, 256, 0, stream>>>(dst, degi, rank);
    prep_feat2<<<(2 * NROWPAD * 28 + 255) / 256, 256, 0, stream>>>(
        node_feat, dyn_emb, hb, h0b);
    prep_small<<<(PS_TOTAL + 255) / 256, 256, 0, stream>>>(
        w1, w2, w1b, w2b, loop_w1, W_ih, W_hh, w1f, wihf, whhf,
        loop_w2, b2, b_ih, b_hh, Mt);

    scanA<<<NB_SCAN, 256, 0, stream>>>(degi, pos, bsum);
    scanC2<<<NB_SCAN, 256, 0, stream>>>(pos, bsum);

    mega2<<<(M2_TOTAL + 255) / 256, 256, 0, stream>>>(
        src, dst, etypes, rank, pos, degi, se, Mt, Mf, biasv);

    // ---- layer 1 (gather reads xb=hb; gemm1 overwrites it in place with h)
    gatherB<<<(N_NODES * 64 + 255) / 256, 256, 0, stream>>>(
        hb, se, pos, degi, w1b, aggp);
    gemm1_kernel<<<(N_NODES + 31) / 32, 256, 0, stream>>>(
        hb, aggp, b1, w1f);

    // ---- layer 2
    gatherB<<<(N_NODES * 64 + 255) / 256, 256, 0, stream>>>(
        hb, se, pos, degi, w2b, aggp);

    // ---- fused layer-2 dense + RNN cell (single phase via M = w2 @ W_ih^T)
    gemm2_kernel<<<(N_NODES + 31) / 32, 256, 0, stream>>>(
        hb, aggp, h0b, Mf, wihf, whhf, biasv, out);
}